// Round 2
// baseline (239.839 us; speedup 1.0000x reference)
//
#include <hip/hip_runtime.h>
#include <math.h>

// CapsNet dynamic routing, fused per-(batch, out_capsule) block. R2:
// - LDS cut to 79.5 KB -> 2 blocks/CU (32 waves/CU, was 1 block/102KB)
// - uhat XOR-quad swizzle instead of pad-20 (bank-conflict-free-ish at stride 16)
// - routing logits b[i] live in REGISTERS (ownership i = t, t+1024)
// - round 0 softmax skipped: softmax(0) == 1/1152 exactly
// - 8 __syncthreads total (was ~30): redundant per-thread reduction finalize
//
// u:      [256][1152][8]  f32
// weight: [1152][10][8][16] f32
// out v:  [256][10][16] f32

#define IC 1152
#define OC 10
#define ID 8
#define OD 16
#define NBATCH 256

// uhat LDS addressing: logical (i, m) -> i*16 + ((((m>>2) ^ (i&3)))<<2) + (m&3)
// Row stride 16 floats (64B). Quad-level XOR swizzle spreads banks so that:
//  - s-pass column reads (fixed m, 4 consecutive rows/wave): 2-way (free, m136)
//  - b-update logical-quad float4 reads: 16 banks/instr (~2-way)
//  - Phase-A float4 writes: 2-way

__global__ __launch_bounds__(1024, 8)
void caps_route_kernel(const float* __restrict__ u,
                       const float* __restrict__ W,
                       float* __restrict__ out) {
    extern __shared__ float smem[];
    float* uhat  = smem;                 // IC*16 = 18432 floats (73728 B)
    float* cexp  = uhat + IC * 16;       // IC
    float* red   = cexp + IC;            // 16 waves * 16 m
    float* wredA = red + 256;            // 16 (max partials)
    float* wredB = wredA + 16;           // 16 (sum partials)

    const int t    = threadIdx.x;
    const int lane = t & 63;
    const int wid  = t >> 6;
    const int bx   = blockIdx.x;

    // XCD-aware (b,j) mapping (perf heuristic: xcd = bx & 7).
    int x = bx & 7, sgrp = bx >> 3;
    int b, j;
    if (sgrp < 256) { j = x; b = sgrp; }
    else { int s2 = sgrp - 256; j = 8 + (x >> 2); b = ((x & 3) << 6) + s2; }

    // ---- Phase A: uhat[i][m] = sum_n u[b,i,n] * W[i,j,n,m] -> LDS ----
    {
        const int mq = t & 3;  // logical quad of the 16-m row
        for (int i = (t >> 2); i < IC; i += 256) {
            const float4* wrow = (const float4*)(W + (size_t)(i * OC + j) * 128);
            const float*  up   = u + (size_t)b * (IC * ID) + i * ID;
            float4 ua = *(const float4*)up;
            float4 ub = *(const float4*)(up + 4);
            float uu[8] = {ua.x, ua.y, ua.z, ua.w, ub.x, ub.y, ub.z, ub.w};
            float4 acc = {0.f, 0.f, 0.f, 0.f};
#pragma unroll
            for (int n = 0; n < 8; ++n) {
                float4 w4 = wrow[n * 4 + mq];
                acc.x += uu[n] * w4.x;
                acc.y += uu[n] * w4.y;
                acc.z += uu[n] * w4.z;
                acc.w += uu[n] * w4.w;
            }
            const int p = mq ^ (i & 3);  // physical quad
            *(float4*)&uhat[i * 16 + (p << 2)] = acc;
        }
    }

    // routing logits in registers: thread t owns i0 = t, and i1 = t+1024 if t<128
    const bool has2 = (t < IC - 1024);
    float b0 = 0.f, b1 = 0.f;

    __syncthreads();  // B0: uhat ready

    const int sg = t >> 4;        // s-pass row group
    const int sm_ = t & 15;       // s-pass m
    // s-pass address pieces: i = sg + 64k -> i&3 == sg&3 constant
    const int soff = (((sm_ >> 2) ^ (sg & 3)) << 2) + (sm_ & 3);

    for (int r = 0; r < 3; ++r) {
        float inv;  // 1 / sum(exp)
        if (r == 0) {
            inv = 1.0f / (float)IC;  // softmax(0) is exactly uniform
        } else {
            // ---- max over b (registers -> wave -> block) ----
            float lm = b0;
            if (has2) lm = fmaxf(lm, b1);
#pragma unroll
            for (int o = 32; o >= 1; o >>= 1) lm = fmaxf(lm, __shfl_xor(lm, o, 64));
            if (lane == 0) wredA[wid] = lm;
            __syncthreads();  // B1
            float mv = wredA[lane & 15];
#pragma unroll
            for (int o = 8; o >= 1; o >>= 1) mv = fmaxf(mv, __shfl_xor(mv, o, 16));
            const float bmax = mv;

            // ---- exp + sum ----
            float e0 = __expf(b0 - bmax);
            cexp[t] = e0;
            float ls = e0;
            if (has2) {
                float e1 = __expf(b1 - bmax);
                cexp[t + 1024] = e1;
                ls += e1;
            }
#pragma unroll
            for (int o = 32; o >= 1; o >>= 1) ls += __shfl_xor(ls, o, 64);
            if (lane == 0) wredB[wid] = ls;
            __syncthreads();  // B2 (also covers cexp writes)
            float sv = wredB[lane & 15];
#pragma unroll
            for (int o = 8; o >= 1; o >>= 1) sv += __shfl_xor(sv, o, 16);
            inv = 1.0f / sv;
        }

        // ---- s[m] = inv * sum_i c[i] * uhat[i][m] ----
        {
            float acc = 0.f;
            if (r == 0) {
#pragma unroll
                for (int k = 0; k < IC / 64; ++k) {
                    int i = sg + 64 * k;
                    acc += uhat[(i << 4) + soff];
                }
            } else {
#pragma unroll
                for (int k = 0; k < IC / 64; ++k) {
                    int i = sg + 64 * k;
                    acc += cexp[i] * uhat[(i << 4) + soff];
                }
            }
            acc += __shfl_xor(acc, 16, 64);
            acc += __shfl_xor(acc, 32, 64);
            if (lane < 16) red[wid * 16 + sm_] = acc;
        }
        __syncthreads();  // B3

        // ---- finalize s + squash, redundantly per thread (m = lane&15) ----
        float smv = 0.f;
#pragma unroll
        for (int w = 0; w < 16; ++w) smv += red[w * 16 + (lane & 15)];
        smv *= inv;
        float p2 = smv * smv;
#pragma unroll
        for (int o = 8; o >= 1; o >>= 1) p2 += __shfl_xor(p2, o, 16);
        // squash scale: s2/(1+s2) / sqrt(s2+eps)
        const float sc = p2 / ((1.0f + p2) * sqrtf(p2 + 1e-8f));
        const float vm = smv * sc;

        if (r == 2) {
            if (t < 16) out[(size_t)(b * OC + j) * OD + t] = vm;
        } else {
            // gather full v[0..15] via width-16 shuffles (no LDS, no barrier)
            float4 v4[4];
#pragma unroll
            for (int k = 0; k < 4; ++k) {
                float a0 = __shfl(vm, 4 * k + 0, 16);
                float a1 = __shfl(vm, 4 * k + 1, 16);
                float a2 = __shfl(vm, 4 * k + 2, 16);
                float a3 = __shfl(vm, 4 * k + 3, 16);
                v4[k] = make_float4(a0, a1, a2, a3);
            }
            // ---- b[i] += v . uhat[i][:] (register blog, logical-quad reads) ----
            {
                const int i = t;
                float dot = 0.f;
#pragma unroll
                for (int k = 0; k < 4; ++k) {
                    const float4 q = *(const float4*)&uhat[(i << 4) + ((k ^ (i & 3)) << 2)];
                    dot += q.x * v4[k].x + q.y * v4[k].y + q.z * v4[k].z + q.w * v4[k].w;
                }
                b0 += dot;
            }
            if (has2) {
                const int i = t + 1024;
                float dot = 0.f;
#pragma unroll
                for (int k = 0; k < 4; ++k) {
                    const float4 q = *(const float4*)&uhat[(i << 4) + ((k ^ (i & 3)) << 2)];
                    dot += q.x * v4[k].x + q.y * v4[k].y + q.z * v4[k].z + q.w * v4[k].w;
                }
                b1 += dot;
            }
        }
    }
}

extern "C" void kernel_launch(void* const* d_in, const int* in_sizes, int n_in,
                              void* d_out, int out_size, void* d_ws, size_t ws_size,
                              hipStream_t stream) {
    const float* u = (const float*)d_in[0];
    const float* W = (const float*)d_in[1];
    float* out = (float*)d_out;

    const size_t shmem = (size_t)(IC * 16 + IC + 256 + 16 + 16) * sizeof(float);  // 79488 B
    hipFuncSetAttribute((const void*)caps_route_kernel,
                        hipFuncAttributeMaxDynamicSharedMemorySize, (int)shmem);

    caps_route_kernel<<<NBATCH * OC, 1024, shmem, stream>>>(u, W, out);
}

// Round 3
// 211.001 us; speedup vs baseline: 1.1367x; 1.1367x over previous
//
#include <hip/hip_runtime.h>
#include <math.h>

// CapsNet dynamic routing, fused per-(batch, out_capsule) block. R3:
// - __launch_bounds__(1024, 1): R2's (1024,8) forced array spills to scratch
//   (307 MB HBM writes, 241 MB fetch). LDS=79.5KB already gives 2 blocks/CU
//   at runtime; the allocator squeeze bought nothing. VGPR ~32 unforced.
// - swizzle now p = mq ^ ((i ^ (i>>2)) & 3): b-update ds_read_b128 covers all
//   32 banks per 8 rows (was 16 banks @ 16-way) while v4[k] index stays a
//   compile-time constant (no dynamic indexing -> no scratch).
// - all small arrays scalarized (uu[8] gone, v4 -> 4 named float4s).
//
// u:      [256][1152][8]  f32
// weight: [1152][10][8][16] f32
// out v:  [256][10][16] f32

#define IC 1152
#define OC 10
#define ID 8
#define OD 16
#define NBATCH 256

// logical (i, m) -> LDS float index: (i<<4) + ((((m>>2) ^ XS(i)) << 2) + (m&3)
#define XS(i) (((i) ^ ((i) >> 2)) & 3)

__global__ __launch_bounds__(1024, 1)
void caps_route_kernel(const float* __restrict__ u,
                       const float* __restrict__ W,
                       float* __restrict__ out) {
    extern __shared__ float smem[];
    float* uhat  = smem;                 // IC*16 = 18432 floats (73728 B)
    float* cexp  = uhat + IC * 16;       // IC
    float* red   = cexp + IC;            // 16 waves * 16 m
    float* wredA = red + 256;            // 16 (max partials)
    float* wredB = wredA + 16;           // 16 (sum partials)

    const int t    = threadIdx.x;
    const int lane = t & 63;
    const int wid  = t >> 6;
    const int bx   = blockIdx.x;

    // XCD-aware (b,j) mapping (perf heuristic: xcd = bx & 7).
    int x = bx & 7, sgrp = bx >> 3;
    int b, j;
    if (sgrp < 256) { j = x; b = sgrp; }
    else { int s2 = sgrp - 256; j = 8 + (x >> 2); b = ((x & 3) << 6) + s2; }

    // ---- Phase A: uhat[i][m] = sum_n u[b,i,n] * W[i,j,n,m] -> LDS ----
    {
        const int mq = t & 3;  // logical quad of the 16-m row
        for (int i = (t >> 2); i < IC; i += 256) {
            const float4* wrow = (const float4*)(W + (size_t)(i * OC + j) * 128);
            const float*  up   = u + (size_t)b * (IC * ID) + i * ID;
            const float4 ua = *(const float4*)up;
            const float4 ub = *(const float4*)(up + 4);
            float4 acc = {0.f, 0.f, 0.f, 0.f};
            float4 w4;
#define PHA_STEP(uu, widx)                                   \
            w4 = wrow[(widx) * 4 + mq];                      \
            acc.x += (uu) * w4.x; acc.y += (uu) * w4.y;      \
            acc.z += (uu) * w4.z; acc.w += (uu) * w4.w;
            PHA_STEP(ua.x, 0) PHA_STEP(ua.y, 1) PHA_STEP(ua.z, 2) PHA_STEP(ua.w, 3)
            PHA_STEP(ub.x, 4) PHA_STEP(ub.y, 5) PHA_STEP(ub.z, 6) PHA_STEP(ub.w, 7)
#undef PHA_STEP
            *(float4*)&uhat[(i << 4) + ((mq ^ XS(i)) << 2)] = acc;
        }
    }

    // routing logits in registers: thread t owns i0 = t, and i1 = t+1024 if t<128
    const bool has2 = (t < IC - 1024);
    float b0 = 0.f, b1 = 0.f;

    __syncthreads();  // B0: uhat ready

    const int sg  = t >> 4;   // s-pass row group (i = sg + 64k -> XS(i) == XS(sg))
    const int sm_ = t & 15;   // s-pass m
    const int soff = ((((sm_ >> 4 ? 0 : sm_ >> 2) ^ XS(sg)) << 2)) + (sm_ & 3);

    for (int r = 0; r < 3; ++r) {
        float inv;  // 1 / sum(exp)
        if (r == 0) {
            inv = 1.0f / (float)IC;  // softmax(0) is exactly uniform
        } else {
            // ---- max over b (registers -> wave -> block) ----
            float lm = b0;
            if (has2) lm = fmaxf(lm, b1);
#pragma unroll
            for (int o = 32; o >= 1; o >>= 1) lm = fmaxf(lm, __shfl_xor(lm, o, 64));
            if (lane == 0) wredA[wid] = lm;
            __syncthreads();  // B1
            float mv = wredA[lane & 15];
#pragma unroll
            for (int o = 8; o >= 1; o >>= 1) mv = fmaxf(mv, __shfl_xor(mv, o, 16));
            const float bmax = mv;

            // ---- exp + sum ----
            float e0 = __expf(b0 - bmax);
            cexp[t] = e0;
            float ls = e0;
            if (has2) {
                float e1 = __expf(b1 - bmax);
                cexp[t + 1024] = e1;
                ls += e1;
            }
#pragma unroll
            for (int o = 32; o >= 1; o >>= 1) ls += __shfl_xor(ls, o, 64);
            if (lane == 0) wredB[wid] = ls;
            __syncthreads();  // B2 (also covers cexp writes)
            float sv = wredB[lane & 15];
#pragma unroll
            for (int o = 8; o >= 1; o >>= 1) sv += __shfl_xor(sv, o, 16);
            inv = 1.0f / sv;
        }

        // ---- s[m] = inv * sum_i c[i] * uhat[i][m] ----
        {
            float acc = 0.f;
            if (r == 0) {
#pragma unroll
                for (int k = 0; k < IC / 64; ++k)
                    acc += uhat[((sg + 64 * k) << 4) + soff];
            } else {
#pragma unroll
                for (int k = 0; k < IC / 64; ++k)
                    acc += cexp[sg + 64 * k] * uhat[((sg + 64 * k) << 4) + soff];
            }
            acc += __shfl_xor(acc, 16, 64);
            acc += __shfl_xor(acc, 32, 64);
            if (lane < 16) red[wid * 16 + sm_] = acc;
        }
        __syncthreads();  // B3

        // ---- finalize s + squash, redundantly per thread (m = lane&15) ----
        float smv = 0.f;
#pragma unroll
        for (int w = 0; w < 16; ++w) smv += red[w * 16 + (lane & 15)];
        smv *= inv;
        float p2 = smv * smv;
#pragma unroll
        for (int o = 8; o >= 1; o >>= 1) p2 += __shfl_xor(p2, o, 16);
        // squash scale: s2/(1+s2) / sqrt(s2+eps)
        const float sc = p2 / ((1.0f + p2) * sqrtf(p2 + 1e-8f));
        const float vm = smv * sc;

        if (r == 2) {
            if (t < 16) out[(size_t)(b * OC + j) * OD + t] = vm;
        } else {
            // gather full v[0..15] via width-16 shuffles (no LDS, no barrier)
            const float4 v4a = make_float4(__shfl(vm, 0, 16),  __shfl(vm, 1, 16),
                                           __shfl(vm, 2, 16),  __shfl(vm, 3, 16));
            const float4 v4b = make_float4(__shfl(vm, 4, 16),  __shfl(vm, 5, 16),
                                           __shfl(vm, 6, 16),  __shfl(vm, 7, 16));
            const float4 v4c = make_float4(__shfl(vm, 8, 16),  __shfl(vm, 9, 16),
                                           __shfl(vm, 10, 16), __shfl(vm, 11, 16));
            const float4 v4d = make_float4(__shfl(vm, 12, 16), __shfl(vm, 13, 16),
                                           __shfl(vm, 14, 16), __shfl(vm, 15, 16));
            // ---- b[i] += v . uhat[i][:] (register blog, swizzled b128 reads) ----
            float4 q;
#define BUP(i, dst)                                                          \
            q = *(const float4*)&uhat[((i) << 4) + ((0 ^ XS(i)) << 2)];      \
            dst += q.x * v4a.x + q.y * v4a.y + q.z * v4a.z + q.w * v4a.w;    \
            q = *(const float4*)&uhat[((i) << 4) + ((1 ^ XS(i)) << 2)];      \
            dst += q.x * v4b.x + q.y * v4b.y + q.z * v4b.z + q.w * v4b.w;    \
            q = *(const float4*)&uhat[((i) << 4) + ((2 ^ XS(i)) << 2)];      \
            dst += q.x * v4c.x + q.y * v4c.y + q.z * v4c.z + q.w * v4c.w;    \
            q = *(const float4*)&uhat[((i) << 4) + ((3 ^ XS(i)) << 2)];      \
            dst += q.x * v4d.x + q.y * v4d.y + q.z * v4d.z + q.w * v4d.w;
            BUP(t, b0)
            if (has2) { BUP(t + 1024, b1) }
#undef BUP
        }
    }
}

extern "C" void kernel_launch(void* const* d_in, const int* in_sizes, int n_in,
                              void* d_out, int out_size, void* d_ws, size_t ws_size,
                              hipStream_t stream) {
    const float* u = (const float*)d_in[0];
    const float* W = (const float*)d_in[1];
    float* out = (float*)d_out;

    const size_t shmem = (size_t)(IC * 16 + IC + 256 + 16 + 16) * sizeof(float);  // 79488 B
    hipFuncSetAttribute((const void*)caps_route_kernel,
                        hipFuncAttributeMaxDynamicSharedMemorySize, (int)shmem);

    caps_route_kernel<<<NBATCH * OC, 1024, shmem, stream>>>(u, W, out);
}